// Round 3
// baseline (226.723 us; speedup 1.0000x reference)
//
#include <hip/hip_runtime.h>
#include <stdint.h>

#define HIDDEN 1024
#define MROWS  32768
#define NPROTO 9
#define ZOFF   (MROWS * NPROTO)   // 294912 floats of logits, then z
#define BM     64
#define BK     32

typedef __bf16 bf16x8 __attribute__((ext_vector_type(8)));
typedef float  f32x4  __attribute__((ext_vector_type(4)));

__device__ __forceinline__ unsigned short f2bf(float f) {
    unsigned u = __float_as_uint(f);
    u += 0x7fffu + ((u >> 16) & 1u);   // round-to-nearest-even
    return (unsigned short)(u >> 16);
}

// ---------------- prep: h (f32) -> bf16 ----------------
__global__ void k_conv_h(const float* __restrict__ src, unsigned short* __restrict__ dst, int n8) {
    int i0 = blockIdx.x * blockDim.x + threadIdx.x;
    int stride = gridDim.x * blockDim.x;
    for (int i = i0; i < n8; i += stride) {
        const float4* p = (const float4*)(src + (size_t)i * 8);
        float4 a = p[0], b = p[1];
        union { unsigned short us[8]; uint4 v; } o;
        o.us[0] = f2bf(a.x); o.us[1] = f2bf(a.y); o.us[2] = f2bf(a.z); o.us[3] = f2bf(a.w);
        o.us[4] = f2bf(b.x); o.us[5] = f2bf(b.y); o.us[6] = f2bf(b.z); o.us[7] = f2bf(b.w);
        *(uint4*)(dst + (size_t)i * 8) = o.v;
    }
}

// ---------------- prep: W*mask -> bf16 ----------------
__global__ void k_conv_w(const float* __restrict__ w, const float* __restrict__ m,
                         unsigned short* __restrict__ dst, int n8) {
    int i0 = blockIdx.x * blockDim.x + threadIdx.x;
    int stride = gridDim.x * blockDim.x;
    for (int i = i0; i < n8; i += stride) {
        const float4* pw = (const float4*)(w + (size_t)i * 8);
        const float4* pm = (const float4*)(m + (size_t)i * 8);
        float4 a = pw[0], b = pw[1], c = pm[0], d = pm[1];
        union { unsigned short us[8]; uint4 v; } o;
        o.us[0] = f2bf(a.x * c.x); o.us[1] = f2bf(a.y * c.y);
        o.us[2] = f2bf(a.z * c.z); o.us[3] = f2bf(a.w * c.w);
        o.us[4] = f2bf(b.x * d.x); o.us[5] = f2bf(b.y * d.y);
        o.us[6] = f2bf(b.z * d.z); o.us[7] = f2bf(b.w * d.w);
        *(uint4*)(dst + (size_t)i * 8) = o.v;
    }
}

// ---------------- prep: l2-normalized prototypes (first 9 rows) ----------------
__global__ void k_proto(const float* __restrict__ proto, float* __restrict__ pn) {
    __shared__ float red[4];
    int t = threadIdx.x, k = blockIdx.x;
    float4 v = *(const float4*)(proto + (size_t)k * HIDDEN + t * 4);
    float ss = v.x * v.x + v.y * v.y + v.z * v.z + v.w * v.w;
    #pragma unroll
    for (int m = 1; m < 64; m <<= 1) ss += __shfl_xor(ss, m);
    if ((t & 63) == 0) red[t >> 6] = ss;
    __syncthreads();
    ss = red[0] + red[1] + red[2] + red[3];
    float inv = 1.0f / fmaxf(sqrtf(ss), 1e-12f);
    float4 o; o.x = v.x * inv; o.y = v.y * inv; o.z = v.z * inv; o.w = v.w * inv;
    *(float4*)(pn + (size_t)k * HIDDEN + t * 4) = o;
}

// ---------------- fused GEMM + LayerNorm + l2norm + logits ----------------
// BM=64, BN=1024 (full N -> each block owns complete z rows), BK=32.
// 8 waves (512 thr): wave w owns all 64 rows x cols [w*128, w*128+128).
// acc[4][8] f32x4 = 128 VGPR. LDS: A dbuf 8K + B dbuf 128K = 136K static.
// Epilogue reuses dead LDS tiles for reductions + protos.
__global__ __launch_bounds__(512, 2) void k_gemm_ln(const unsigned short* __restrict__ A,
                                                    const unsigned short* __restrict__ B,
                                                    const float* __restrict__ gamma,
                                                    const float* __restrict__ beta,
                                                    const float* __restrict__ pn,
                                                    float* __restrict__ z,
                                                    float* __restrict__ logits) {
    __shared__ char smem[139264];   // [0,8K) A dbuf, [8K,136K) B dbuf
    const int tid = threadIdx.x;
    const int wid = tid >> 6, lane = tid & 63;
    const int fr = lane & 15, kq = lane >> 4;
    const int bm0 = (int)blockIdx.x * BM;

    f32x4 acc[4][8] = {};

    auto stage = [&](int buf, int k0) {
        // A tile: 64 rows x 32 k = 4 KB = 256 chunks of 16B; waves 0..3
        if (wid < 4) {
            int row = tid >> 2, seg = tid & 3;
            const unsigned short* ga = A + (size_t)(bm0 + row) * HIDDEN + k0 + seg * 8;
            void* la = (void*)(smem + (buf ? 4096 : 0) + (size_t)wid * 1024);
            __builtin_amdgcn_global_load_lds((const __attribute__((address_space(1))) void*)ga,
                                             (__attribute__((address_space(3))) void*)la, 16, 0, 0);
        }
        // B tile: 1024 rows x 32 k = 64 KB = 4096 chunks; 8 rounds x 512 thr
        #pragma unroll
        for (int ir = 0; ir < 8; ir++) {
            int c = ir * 512 + tid;
            int row = c >> 2, seg = c & 3;
            const unsigned short* gb = B + (size_t)row * HIDDEN + k0 + seg * 8;
            void* lb = (void*)(smem + 8192 + (buf ? 65536 : 0) + (size_t)(ir * 512 + wid * 64) * 16);
            __builtin_amdgcn_global_load_lds((const __attribute__((address_space(1))) void*)gb,
                                             (__attribute__((address_space(3))) void*)lb, 16, 0, 0);
        }
    };

    auto compute = [&](int buf) {
        const unsigned short* as = (const unsigned short*)(smem + (buf ? 4096 : 0));
        const unsigned short* bs = (const unsigned short*)(smem + 8192 + (buf ? 65536 : 0));
        bf16x8 av[4], bv[8];
        #pragma unroll
        for (int i = 0; i < 4; i++)
            av[i] = *(const bf16x8*)&as[(i * 16 + fr) * BK + kq * 8];
        #pragma unroll
        for (int j = 0; j < 8; j++)
            bv[j] = *(const bf16x8*)&bs[(wid * 128 + j * 16 + fr) * BK + kq * 8];
        #pragma unroll
        for (int i = 0; i < 4; i++)
            #pragma unroll
            for (int j = 0; j < 8; j++)
                acc[i][j] = __builtin_amdgcn_mfma_f32_16x16x32_bf16(av[i], bv[j], acc[i][j], 0, 0, 0);
    };

    stage(0, 0);
    __syncthreads();
    int cur = 0;
    for (int t = 1; t < HIDDEN / BK; t++) {
        stage(cur ^ 1, t * BK);
        compute(cur);
        __syncthreads();
        cur ^= 1;
    }
    compute(cur);
    __syncthreads();   // tiles dead below this point

    // ---- epilogue LDS overlays (all within dead tile regions) ----
    float* red_s     = (float*)smem;              // [8][64]
    float* red_sq    = (float*)(smem + 2048);     // [8][64]
    float* mu_lds    = (float*)(smem + 4096);     // [64]
    float* rs_lds    = (float*)(smem + 4352);     // [64]
    float* proto_lds = (float*)(smem + 8192);     // [9][1024]
    float* part_lds  = (float*)(smem + 45056);    // [64][8][10]

    // stage normalized protos (36 KB)
    #pragma unroll
    for (int i2 = 0; i2 < 5; i2++) {
        int idx = i2 * 512 + tid;
        if (idx < NPROTO * HIDDEN / 4) ((float4*)proto_lds)[idx] = ((const float4*)pn)[idx];
    }

    // per-(wave,row) s/sq partials over this wave's 128 cols
    #pragma unroll
    for (int i = 0; i < 4; i++) {
        #pragma unroll
        for (int r = 0; r < 4; r++) {
            float s = 0.f, sq = 0.f;
            #pragma unroll
            for (int j = 0; j < 8; j++) { float v = acc[i][j][r]; s += v; sq += v * v; }
            #pragma unroll
            for (int m = 1; m < 16; m <<= 1) { s += __shfl_xor(s, m); sq += __shfl_xor(sq, m); }
            if (fr == 0) {
                int row = i * 16 + kq * 4 + r;
                red_s[wid * 64 + row] = s;
                red_sq[wid * 64 + row] = sq;
            }
        }
    }
    __syncthreads();

    if (tid < 64) {
        float s = 0.f, sq = 0.f;
        #pragma unroll
        for (int w = 0; w < 8; w++) { s += red_s[w * 64 + tid]; sq += red_sq[w * 64 + tid]; }
        float mu = s * (1.0f / 1024.0f);
        float var = sq * (1.0f / 1024.0f) - mu * mu;
        mu_lds[tid] = mu;
        rs_lds[tid] = rsqrtf(var + 1e-5f);
    }
    __syncthreads();

    // gamma/beta for this lane's 8 columns
    float g[8], b[8];
    #pragma unroll
    for (int j = 0; j < 8; j++) {
        int col = wid * 128 + j * 16 + fr;
        g[j] = gamma[col];
        b[j] = beta[col];
    }

    // LN transform in-place + write z
    #pragma unroll
    for (int i = 0; i < 4; i++) {
        #pragma unroll
        for (int r = 0; r < 4; r++) {
            int row = i * 16 + kq * 4 + r;
            float mu = mu_lds[row], rs = rs_lds[row];
            float* zr = z + (size_t)(bm0 + row) * HIDDEN + wid * 128;
            #pragma unroll
            for (int j = 0; j < 8; j++) {
                float v = (acc[i][j][r] - mu) * rs * g[j] + b[j];
                acc[i][j][r] = v;
                zr[j * 16 + fr] = v;
            }
        }
    }

    // ss partials per row
    #pragma unroll
    for (int i = 0; i < 4; i++) {
        #pragma unroll
        for (int r = 0; r < 4; r++) {
            float ss = 0.f;
            #pragma unroll
            for (int j = 0; j < 8; j++) { float v = acc[i][j][r]; ss += v * v; }
            #pragma unroll
            for (int m = 1; m < 16; m <<= 1) ss += __shfl_xor(ss, m);
            if (fr == 0) {
                int row = i * 16 + kq * 4 + r;
                part_lds[(row * 8 + wid) * 10 + 9] = ss;
            }
        }
    }
    // proto-dot partials per row
    for (int k = 0; k < NPROTO; k++) {
        float p[8];
        #pragma unroll
        for (int j = 0; j < 8; j++) p[j] = proto_lds[k * HIDDEN + wid * 128 + j * 16 + fr];
        #pragma unroll
        for (int i = 0; i < 4; i++) {
            #pragma unroll
            for (int r = 0; r < 4; r++) {
                float d = 0.f;
                #pragma unroll
                for (int j = 0; j < 8; j++) d += acc[i][j][r] * p[j];
                #pragma unroll
                for (int m = 1; m < 16; m <<= 1) d += __shfl_xor(d, m);
                if (fr == 0) {
                    int row = i * 16 + kq * 4 + r;
                    part_lds[(row * 8 + wid) * 10 + k] = d;
                }
            }
        }
    }
    __syncthreads();

    if (tid < 64) {
        int row = tid;
        float dot[NPROTO];
        #pragma unroll
        for (int k = 0; k < NPROTO; k++) dot[k] = 0.f;
        float ss = 0.f;
        #pragma unroll
        for (int w = 0; w < 8; w++) {
            const float* pl = &part_lds[(row * 8 + w) * 10];
            #pragma unroll
            for (int k = 0; k < NPROTO; k++) dot[k] += pl[k];
            ss += pl[9];
        }
        float inv = 1.0f / (fmaxf(sqrtf(ss), 1e-12f) * 0.07f);
        float* lr = logits + (size_t)(bm0 + row) * NPROTO;
        #pragma unroll
        for (int k = 0; k < NPROTO; k++) lr[k] = dot[k] * inv;
    }
}

extern "C" void kernel_launch(void* const* d_in, const int* in_sizes, int n_in,
                              void* d_out, int out_size, void* d_ws, size_t ws_size,
                              hipStream_t stream) {
    const float* h     = (const float*)d_in[0];
    const float* w     = (const float*)d_in[1];
    const float* mask  = (const float*)d_in[2];
    const float* gamma = (const float*)d_in[3];
    const float* beta  = (const float*)d_in[4];
    const float* proto = (const float*)d_in[5];
    float* out    = (float*)d_out;
    float* logits = out;                       // 32768*9 floats
    float* z      = out + (size_t)ZOFF;        // 32768*1024 floats

    char* ws = (char*)d_ws;
    unsigned short* hb = (unsigned short*)ws;                        // 64 MB bf16 h
    unsigned short* wm = (unsigned short*)(ws + 67108864);           // 2 MB bf16 W*mask
    float*          pn = (float*)(ws + 67108864 + 2097152);          // 36 KB normalized protos

    k_conv_h<<<4096, 256, 0, stream>>>(h, hb, MROWS * HIDDEN / 8);
    k_conv_w<<<512, 256, 0, stream>>>(w, mask, wm, HIDDEN * HIDDEN / 8);
    k_proto<<<NPROTO, 256, 0, stream>>>(proto, pn);
    k_gemm_ln<<<MROWS / BM, 512, 0, stream>>>(hb, wm, gamma, beta, pn, z, logits);
}